// Round 12
// baseline (1055.968 us; speedup 1.0000x reference)
//
#include <hip/hip_runtime.h>
#include <hip/hip_bf16.h>

// Problem constants (from setup_inputs)
#define N_NODES 20000
#define NANG 8
#define CH 64                      // in_size == out_size == 64
#define M_ROWS (NANG * N_NODES)    // 160000
#define E_EDGES (M_ROWS * 16)      // 2560000
#define K_CHEB 8
#define WK_STRIDE (NANG * CH * CH) // 32768 floats per weight[k]
#define BROWS 256                  // rows per bucket (good scatter write-combining)
#define NB (M_ROWS / BROWS)        // 625 buckets
#define NCHUNK 320
#define CHUNK (E_EDGES / NCHUNK)   // 8000
#define SPMM_BLOCKS (M_ROWS / 8)   // 20000 (2 rows/wave, 4 waves/block)
#define KCAT 3648                  // 64 (x@Wsum) + 7*512 (feat(Tk)@Wk)
#define SK_TOTAL 114               // KCAT/32 ksteps
#define SK_PAD 116                 // padded to 4*29 (pad ksteps have zero W)
#define KCAT2 (SK_PAD * 32)        // 3712
#define BCAP 5120                  // LDS staging cap (mean 4096, sd 64 -> 16 sigma)

typedef short short8 __attribute__((ext_vector_type(8)));
typedef float f32x4 __attribute__((ext_vector_type(4)));

__device__ __forceinline__ float bf2f(ushort u) {
    return __uint_as_float((unsigned int)u << 16);
}

// ---------------- deterministic bucket build (no global atomics) ----------------

__global__ __launch_bounds__(256) void count_kernel(const int* __restrict__ rows,
                                                    int* __restrict__ chunk_cnt) {
    __shared__ int h[NB];
    int c = blockIdx.x, tid = threadIdx.x;
    for (int i = tid; i < NB; i += 256) h[i] = 0;
    __syncthreads();
    int base = c * CHUNK;
    for (int i = tid; i < CHUNK; i += 256) atomicAdd(&h[rows[base + i] >> 8], 1);
    __syncthreads();
    for (int i = tid; i < NB; i += 256) chunk_cnt[(size_t)c * NB + i] = h[i];
}

__global__ void btotal_kernel(const int* __restrict__ chunk_cnt, int* __restrict__ btotal) {
    int b = blockIdx.x * 256 + threadIdx.x;
    if (b >= NB) return;
    int s = 0;
    for (int c = 0; c < NCHUNK; ++c) s += chunk_cnt[(size_t)c * NB + b];
    btotal[b] = s;
}

// single-block exclusive scan over NB bucket totals (NB=625 <= 1024)
__global__ void bscan_kernel(const int* __restrict__ btotal, int* __restrict__ bstart) {
    __shared__ int s[1024];
    int t = threadIdx.x;
    int v = (t < NB) ? btotal[t] : 0;
    s[t] = v;
    __syncthreads();
    for (int off = 1; off < 1024; off <<= 1) {
        int u = (t >= off) ? s[t - off] : 0;
        __syncthreads();
        s[t] += u;
        __syncthreads();
    }
    if (t < NB) bstart[t] = s[t] - v;
    if (t == 1023) bstart[NB] = s[1023];
}

// chunk_cnt -> per-(chunk,bucket) write offsets, in place
__global__ void offs_kernel(int* __restrict__ chunk_cnt, const int* __restrict__ bstart) {
    int b = blockIdx.x * 256 + threadIdx.x;
    if (b >= NB) return;
    int run = bstart[b];
    for (int c = 0; c < NCHUNK; ++c) {
        int v = chunk_cnt[(size_t)c * NB + b];
        chunk_cnt[(size_t)c * NB + b] = run;
        run += v;
    }
}

// scatter into bucket-ordered streams (LDS-local offsets, sequential per-bucket writes)
__global__ __launch_bounds__(256) void scatter_kernel(
        const int* __restrict__ rows, const int* __restrict__ cols,
        const float* __restrict__ vals, const int* __restrict__ chunk_cnt,
        int2* __restrict__ bedges) {
    __shared__ int loff[NB];
    int c = blockIdx.x, tid = threadIdx.x;
    for (int i = tid; i < NB; i += 256) loff[i] = chunk_cnt[(size_t)c * NB + i];
    __syncthreads();
    int base = c * CHUNK;
    for (int i = tid; i < CHUNK; i += 256) {
        int e = base + i;
        int r = rows[e];
        int p = atomicAdd(&loff[r >> 8], 1);
        bedges[p] = make_int2(cols[e] | ((r & 255) << 18), __float_as_int(vals[e]));
    }
}

// per-bucket: group edges by row via LDS staging, then write bout SEQUENTIALLY
__global__ __launch_bounds__(256) void bucket_group_kernel(
        const int* __restrict__ bstart, const int2* __restrict__ bin,
        int2* __restrict__ bout, int* __restrict__ row_start) {
    __shared__ int cnt[BROWS];
    __shared__ int pref[BROWS];
    __shared__ int fill[BROWS];
    __shared__ int2 ob[BCAP];          // 40 KB staging
    int b = blockIdx.x, tid = threadIdx.x;
    int s = bstart[b], e = bstart[b + 1];
    int n = e - s;
    cnt[tid] = 0;
    __syncthreads();
    int2 eds[20];                      // reg cache (n/256 <= 20 when n <= BCAP)
    int ni = 0;
    for (int i = tid; i < n; i += 256, ++ni) {
        int2 ed = bin[s + i];
        if (ni < 20) eds[ni] = ed;
        atomicAdd(&cnt[(ed.x >> 18) & 255], 1);
    }
    __syncthreads();
    int v = cnt[tid];
    pref[tid] = v;
    __syncthreads();
#pragma unroll
    for (int off = 1; off < 256; off <<= 1) {
        int u = (tid >= off) ? pref[tid - off] : 0;
        __syncthreads();
        pref[tid] += u;
        __syncthreads();
    }
    int my_excl = pref[tid] - v;
    __syncthreads();
    pref[tid] = my_excl;
    fill[tid] = my_excl;
    __syncthreads();

    if (n <= BCAP) {
        ni = 0;
        for (int i = tid; i < n; i += 256, ++ni) {
            int2 ed = (ni < 20) ? eds[ni] : bin[s + i];
            int p = atomicAdd(&fill[(ed.x >> 18) & 255], 1);
            ob[p] = make_int2(ed.x & 0x3ffff, ed.y);
        }
        __syncthreads();
        for (int i = tid; i < n; i += 256)
            bout[s + i] = ob[i];       // sequential, coalesced
    } else {
        ni = 0;
        for (int i = tid; i < n; i += 256, ++ni) {
            int2 ed = (ni < 20) ? eds[ni] : bin[s + i];
            int p = atomicAdd(&fill[(ed.x >> 18) & 255], 1);
            bout[s + p] = make_int2(ed.x & 0x3ffff, ed.y);
        }
    }
    row_start[b * BROWS + tid] = s + pref[tid];
    if (b == NB - 1 && tid == 0) row_start[M_ROWS] = e;
}

// ---------------- small converts ----------------

__global__ void xconv_kernel(const float* __restrict__ x, ushort* __restrict__ xb) {
    int i = blockIdx.x * 256 + threadIdx.x;
    __hip_bfloat16 v = __float2bfloat16(x[i]);
    xb[i] = *(ushort*)&v;
}

// Wcat[n][kkc]: kkc<64 -> sum_a W[0][a*64+kkc][n]; 64<=kkc<KCAT -> W[k][kk][n]; else 0.
__global__ void wcat_kernel(const float* __restrict__ W, ushort* __restrict__ Wcat) {
    int idx = blockIdx.x * 256 + threadIdx.x;    // 64*KCAT2
    int n   = idx / KCAT2;
    int kkc = idx - n * KCAT2;
    float v;
    if (kkc < 64) {
        v = 0.f;
#pragma unroll
        for (int a = 0; a < NANG; ++a) v += W[(a * 64 + kkc) * 64 + n];
    } else if (kkc < KCAT) {
        int k  = ((kkc - 64) >> 9) + 1;
        int kk = (kkc - 64) & 511;
        v = W[(size_t)k * WK_STRIDE + kk * 64 + n];
    } else {
        v = 0.f;
    }
    __hip_bfloat16 b = __float2bfloat16(v);
    Wcat[idx] = *(ushort*)&b;
}

// ---------------- SpMM: 2 rows per wave, ushort2 channels, readlane broadcast ------
// Lanes 0-31: row rA (channels 2*li, 2*li+1); lanes 32-63: row rB. One coalesced
// edge-load stages 16 edges of each row (lanes 0-15: A, 16-31: B); each gather
// instruction fetches BOTH rows' 128B lines (256B) -> 2x in-flight bytes/wave.
// TIN_TILED: Tin is xb [N,64], col % N_NODES. TSUB_MODE: 0 none, 1 [M,64], 2 xb tiled.

template <int TIN_TILED, int TSUB_MODE>
__global__ __launch_bounds__(256) void spmm_kernel(
        const int* __restrict__ row_start, const int2* __restrict__ edges,
        const ushort* __restrict__ Tin, const ushort* __restrict__ Tsub,
        ushort* __restrict__ Tout, float alpha, float beta) {
    int wv = (blockIdx.x * 256 + threadIdx.x) >> 6;
    int lane = threadIdx.x & 63;
    int rA = wv * 2;
    if (rA >= M_ROWS) return;
    int li = lane & 31;
    int half = lane >> 5;              // 0: row A, 1: row B
    int sA = row_start[rA];
    int eA = row_start[rA + 1];
    int eB = row_start[rA + 2];
    int sB = eA;
    int nA = eA - sA, nB = eB - sB;
    int nmax = max(nA, nB);
    float acc0 = 0.f, acc1 = 0.f;
    for (int b = 0; b < nmax; b += 16) {
        int j = li & 15;
        int idx = (li >> 4) ? min(sB + b + j, eB - 1) : min(sA + b + j, eA - 1);
        idx = max(idx, 0);
        int2 ed = edges[idx];          // 32 edges (16/row), 256B coalesced
#pragma unroll
        for (int i = 0; i < 16; ++i) {
            int colA = __builtin_amdgcn_readlane(ed.x, i);
            int wAi  = __builtin_amdgcn_readlane(ed.y, i);
            int colB = __builtin_amdgcn_readlane(ed.x, 16 + i);
            int wBi  = __builtin_amdgcn_readlane(ed.y, 16 + i);
            int col  = half ? colB : colA;
            float w  = __int_as_float(half ? wBi : wAi);
            int n    = half ? nB : nA;
            if (b + i >= n) w = 0.f;
            unsigned c = (unsigned)col;
            if (TIN_TILED) c %= N_NODES;
            unsigned t2 = *(const unsigned*)(Tin + (size_t)c * CH + 2 * li);
            acc0 = fmaf(w, __uint_as_float(t2 << 16), acc0);
            acc1 = fmaf(w, __uint_as_float(t2 & 0xffff0000u), acc1);
        }
    }
    int r = rA + half;
    size_t oi = (size_t)r * CH + 2 * li;
    float v0 = alpha * acc0, v1 = alpha * acc1;
    if (TSUB_MODE) {
        size_t si = (TSUB_MODE == 2) ? (size_t)((unsigned)r % N_NODES) * CH + 2 * li : oi;
        unsigned s2 = *(const unsigned*)(Tsub + si);
        v0 += beta * __uint_as_float(s2 << 16);
        v1 += beta * __uint_as_float(s2 & 0xffff0000u);
    }
    __hip_bfloat16 o0 = __float2bfloat16(v0);
    __hip_bfloat16 o1 = __float2bfloat16(v1);
    unsigned ov = (unsigned)(*(ushort*)&o0) | ((unsigned)(*(ushort*)&o1) << 16);
    *(unsigned*)(Tout + oi) = ov;
}

// ---------------- concatenated GEMM: 5000 independent single-wave blocks ----------
// out += partial([x | feat(T1..T7)] @ Wcat) via fp32 atomicAdd (out pre-zeroed).
// block = 1 wave = (16-row tile, 29-kstep chunk); A AND B prefetched 3-ahead in a
// 4-slot register ring (no LDS, no barrier -> scheduler-friendly, all co-resident).
// A layout: m=lane&15, k=(lane>>4)*8+j. C/D: col=lane&15, row=(lane>>4)*4+reg [m89].

__global__ __launch_bounds__(64) void gemm_cat_kernel(
        const ushort* __restrict__ xb,    // [N,64]
        const ushort* __restrict__ Tall,  // [7][NANG*N,64]
        const ushort* __restrict__ Wcat,  // [64][KCAT2]
        const float* __restrict__ bias,
        float* __restrict__ out) {        // [N,64] fp32, pre-zeroed
    int tile = blockIdx.x >> 2;
    int w    = blockIdx.x & 3;
    int m0 = tile * 16;
    int l = threadIdx.x;
    int lm = l & 15;
    int lq = l >> 4;
    const short* Xp = (const short*)xb;
    const short* Tp = (const short*)Tall;
    const short* Wp = (const short*)Wcat;

    auto loadA = [&](int sk) -> short8 {
        sk = min(sk, SK_TOTAL - 1);
        const short* p;
        if (sk < 2) {
            p = Xp + (size_t)(m0 + lm) * CH + sk * 32 + lq * 8;
        } else {
            int seg = (sk - 2) >> 4, ks = (sk - 2) & 15;
            int a = ks >> 1, hf = ks & 1;
            p = Tp + (size_t)seg * M_ROWS * CH
                + ((size_t)(a * N_NODES + m0 + lm)) * CH + hf * 32 + lq * 8;
        }
        return *(const short8*)p;
    };

    f32x4 acc[4];
#pragma unroll
    for (int t = 0; t < 4; ++t) acc[t] = (f32x4){0.f, 0.f, 0.f, 0.f};

    int sk0 = w * 29;
    short8 ab[4];
    short8 bb[4][4];
#pragma unroll
    for (int p = 0; p < 3; ++p) {
        ab[p] = loadA(sk0 + p);
#pragma unroll
        for (int t = 0; t < 4; ++t)
            bb[p][t] = *(const short8*)(Wp + (size_t)(t * 16 + lm) * KCAT2 + (sk0 + p) * 32 + lq * 8);
    }

#pragma unroll
    for (int i = 0; i < 29; ++i) {
        int pre = i + 3;
        if (pre < 29) {
            int slot = pre & 3;            // slot consumed at iter i-1 -> free
            ab[slot] = loadA(sk0 + pre);
#pragma unroll
            for (int t = 0; t < 4; ++t)
                bb[slot][t] = *(const short8*)(Wp + (size_t)(t * 16 + lm) * KCAT2 + (sk0 + pre) * 32 + lq * 8);
        }
        int cur = i & 3;
#pragma unroll
        for (int t = 0; t < 4; ++t)
            acc[t] = __builtin_amdgcn_mfma_f32_16x16x32_bf16(ab[cur], bb[cur][t], acc[t], 0, 0, 0);
    }

#pragma unroll
    for (int t = 0; t < 4; ++t) {
        int col = t * 16 + lm;
#pragma unroll
        for (int rI = 0; rI < 4; ++rI) {
            float v = acc[t][rI];
            if (w == 0) v += bias[col];
            atomicAdd(&out[(size_t)(m0 + lq * 4 + rI) * CH + col], v);
        }
    }
}

// ---------------- launch ----------------

extern "C" void kernel_launch(void* const* d_in, const int* in_sizes, int n_in,
                              void* d_out, int out_size, void* d_ws, size_t ws_size,
                              hipStream_t stream) {
    (void)in_sizes; (void)n_in; (void)out_size; (void)ws_size;
    const float* x       = (const float*)d_in[0];
    const float* ls_vals = (const float*)d_in[1];
    const float* weight  = (const float*)d_in[2];
    const float* bias    = (const float*)d_in[3];
    const int*   ls_rows = (const int*)d_in[4];
    const int*   ls_cols = (const int*)d_in[5];
    float* out = (float*)d_out;

    char* ws = (char*)d_ws;
    size_t off = 0;
    auto alloc = [&](size_t bytes) -> void* {
        void* p = ws + off;
        off += (bytes + 255) & ~(size_t)255;
        return p;
    };
    int*  chunk_cnt = (int*)alloc((size_t)NCHUNK * NB * sizeof(int));
    int*  btotal    = (int*)alloc(NB * sizeof(int));
    int*  bstart    = (int*)alloc((NB + 1) * sizeof(int));
    int*  row_start = (int*)alloc((M_ROWS + 1) * sizeof(int));
    int2* bedges2   = (int2*)alloc((size_t)E_EDGES * sizeof(int2));
    ushort* Wcat = (ushort*)alloc((size_t)64 * KCAT2 * sizeof(ushort));
    ushort* xb   = (ushort*)alloc((size_t)N_NODES * CH * sizeof(ushort));
    ushort* Tall = (ushort*)alloc((size_t)7 * M_ROWS * CH * sizeof(ushort));
    // Alias: phase-1 bucket staging lives in Tall seg0 (dead before spmm#1 writes it)
    int2* bedges = (int2*)Tall;

    // zero the output accumulator (gemm_cat uses atomicAdd)
    hipMemsetAsync(out, 0, (size_t)N_NODES * CH * sizeof(float), stream);

    // deterministic bucket build + per-bucket row grouping
    count_kernel<<<NCHUNK, 256, 0, stream>>>(ls_rows, chunk_cnt);
    btotal_kernel<<<(NB + 255) / 256, 256, 0, stream>>>(chunk_cnt, btotal);
    bscan_kernel<<<1, 1024, 0, stream>>>(btotal, bstart);
    offs_kernel<<<(NB + 255) / 256, 256, 0, stream>>>(chunk_cnt, bstart);
    scatter_kernel<<<NCHUNK, 256, 0, stream>>>(ls_rows, ls_cols, ls_vals, chunk_cnt, bedges);
    bucket_group_kernel<<<NB, 256, 0, stream>>>(bstart, bedges, bedges2, row_start);

    // converts
    xconv_kernel<<<(N_NODES * CH) / 256, 256, 0, stream>>>(x, xb);
    wcat_kernel<<<(64 * KCAT2) / 256, 256, 0, stream>>>(weight, Wcat);

    ushort* T[8];  // T[k] = seg k-1
    for (int k = 1; k < K_CHEB; ++k) T[k] = Tall + (size_t)(k - 1) * M_ROWS * CH;

    // Chebyshev chain (T1 = L tile(x); Tk = 2 L T_{k-1} - T_{k-2})
    spmm_kernel<1, 0><<<SPMM_BLOCKS, 256, 0, stream>>>(
        row_start, bedges2, xb, xb, T[1], 1.f, 0.f);
    spmm_kernel<0, 2><<<SPMM_BLOCKS, 256, 0, stream>>>(
        row_start, bedges2, T[1], xb, T[2], 2.f, -1.f);
    for (int k = 3; k < K_CHEB; ++k) {
        spmm_kernel<0, 1><<<SPMM_BLOCKS, 256, 0, stream>>>(
            row_start, bedges2, T[k - 1], T[k - 2], T[k], 2.f, -1.f);
    }

    // one concatenated GEMM for all k terms (4 k-chunks per 16-row tile)
    gemm_cat_kernel<<<(N_NODES / 16) * 4, 64, 0, stream>>>(xb, Tall, Wcat, bias, out);
}

// Round 13
// 744.078 us; speedup vs baseline: 1.4192x; 1.4192x over previous
//
#include <hip/hip_runtime.h>
#include <hip/hip_bf16.h>

// Problem constants (from setup_inputs)
#define N_NODES 20000
#define NANG 8
#define CH 64                      // in_size == out_size == 64
#define M_ROWS (NANG * N_NODES)    // 160000
#define E_EDGES (M_ROWS * 16)      // 2560000
#define K_CHEB 8
#define WK_STRIDE (NANG * CH * CH) // 32768 floats per weight[k]
#define BROWS 256                  // rows per bucket (good scatter write-combining)
#define NB (M_ROWS / BROWS)        // 625 buckets
#define NCHUNK 320
#define CHUNK (E_EDGES / NCHUNK)   // 8000
#define SPMM_BLOCKS (M_ROWS / 4)   // 40000 (1 row/wave, 4 waves/block)
#define KCAT 3648                  // 64 (x@Wsum) + 7*512 (feat(Tk)@Wk)
#define SK_TOTAL 114               // KCAT/32 ksteps
#define SK_PAD 116                 // padded to 4*29 (pad ksteps have zero W)
#define KCAT2 (SK_PAD * 32)        // 3712
#define BCAP 5120                  // LDS staging cap (mean 4096, sd 64 -> 16 sigma)

typedef short short8 __attribute__((ext_vector_type(8)));
typedef float f32x4 __attribute__((ext_vector_type(4)));

__device__ __forceinline__ float bf2f(ushort u) {
    return __uint_as_float((unsigned int)u << 16);
}

// ---------------- deterministic bucket build (no global atomics) ----------------

__global__ __launch_bounds__(256) void count_kernel(const int* __restrict__ rows,
                                                    int* __restrict__ chunk_cnt) {
    __shared__ int h[NB];
    int c = blockIdx.x, tid = threadIdx.x;
    for (int i = tid; i < NB; i += 256) h[i] = 0;
    __syncthreads();
    int base = c * CHUNK;
    for (int i = tid; i < CHUNK; i += 256) atomicAdd(&h[rows[base + i] >> 8], 1);
    __syncthreads();
    for (int i = tid; i < NB; i += 256) chunk_cnt[(size_t)c * NB + i] = h[i];
}

__global__ void btotal_kernel(const int* __restrict__ chunk_cnt, int* __restrict__ btotal) {
    int b = blockIdx.x * 256 + threadIdx.x;
    if (b >= NB) return;
    int s = 0;
    for (int c = 0; c < NCHUNK; ++c) s += chunk_cnt[(size_t)c * NB + b];
    btotal[b] = s;
}

// single-block exclusive scan over NB bucket totals (NB=625 <= 1024)
__global__ void bscan_kernel(const int* __restrict__ btotal, int* __restrict__ bstart) {
    __shared__ int s[1024];
    int t = threadIdx.x;
    int v = (t < NB) ? btotal[t] : 0;
    s[t] = v;
    __syncthreads();
    for (int off = 1; off < 1024; off <<= 1) {
        int u = (t >= off) ? s[t - off] : 0;
        __syncthreads();
        s[t] += u;
        __syncthreads();
    }
    if (t < NB) bstart[t] = s[t] - v;
    if (t == 1023) bstart[NB] = s[1023];
}

// chunk_cnt -> per-(chunk,bucket) write offsets, in place
__global__ void offs_kernel(int* __restrict__ chunk_cnt, const int* __restrict__ bstart) {
    int b = blockIdx.x * 256 + threadIdx.x;
    if (b >= NB) return;
    int run = bstart[b];
    for (int c = 0; c < NCHUNK; ++c) {
        int v = chunk_cnt[(size_t)c * NB + b];
        chunk_cnt[(size_t)c * NB + b] = run;
        run += v;
    }
}

// scatter into bucket-ordered streams (LDS-local offsets, sequential per-bucket writes)
__global__ __launch_bounds__(256) void scatter_kernel(
        const int* __restrict__ rows, const int* __restrict__ cols,
        const float* __restrict__ vals, const int* __restrict__ chunk_cnt,
        int2* __restrict__ bedges) {
    __shared__ int loff[NB];
    int c = blockIdx.x, tid = threadIdx.x;
    for (int i = tid; i < NB; i += 256) loff[i] = chunk_cnt[(size_t)c * NB + i];
    __syncthreads();
    int base = c * CHUNK;
    for (int i = tid; i < CHUNK; i += 256) {
        int e = base + i;
        int r = rows[e];
        int p = atomicAdd(&loff[r >> 8], 1);
        bedges[p] = make_int2(cols[e] | ((r & 255) << 18), __float_as_int(vals[e]));
    }
}

// per-bucket: group edges by row via LDS staging, then write bout SEQUENTIALLY
__global__ __launch_bounds__(256) void bucket_group_kernel(
        const int* __restrict__ bstart, const int2* __restrict__ bin,
        int2* __restrict__ bout, int* __restrict__ row_start) {
    __shared__ int cnt[BROWS];
    __shared__ int pref[BROWS];
    __shared__ int fill[BROWS];
    __shared__ int2 ob[BCAP];          // 40 KB staging
    int b = blockIdx.x, tid = threadIdx.x;
    int s = bstart[b], e = bstart[b + 1];
    int n = e - s;
    cnt[tid] = 0;
    __syncthreads();
    int2 eds[20];                      // reg cache (n/256 <= 20 when n <= BCAP)
    int ni = 0;
    for (int i = tid; i < n; i += 256, ++ni) {
        int2 ed = bin[s + i];
        if (ni < 20) eds[ni] = ed;
        atomicAdd(&cnt[(ed.x >> 18) & 255], 1);
    }
    __syncthreads();
    int v = cnt[tid];
    pref[tid] = v;
    __syncthreads();
#pragma unroll
    for (int off = 1; off < 256; off <<= 1) {
        int u = (tid >= off) ? pref[tid - off] : 0;
        __syncthreads();
        pref[tid] += u;
        __syncthreads();
    }
    int my_excl = pref[tid] - v;
    __syncthreads();
    pref[tid] = my_excl;
    fill[tid] = my_excl;
    __syncthreads();

    if (n <= BCAP) {
        ni = 0;
        for (int i = tid; i < n; i += 256, ++ni) {
            int2 ed = (ni < 20) ? eds[ni] : bin[s + i];
            int p = atomicAdd(&fill[(ed.x >> 18) & 255], 1);
            ob[p] = make_int2(ed.x & 0x3ffff, ed.y);
        }
        __syncthreads();
        for (int i = tid; i < n; i += 256)
            bout[s + i] = ob[i];       // sequential, coalesced
    } else {
        ni = 0;
        for (int i = tid; i < n; i += 256, ++ni) {
            int2 ed = (ni < 20) ? eds[ni] : bin[s + i];
            int p = atomicAdd(&fill[(ed.x >> 18) & 255], 1);
            bout[s + p] = make_int2(ed.x & 0x3ffff, ed.y);
        }
    }
    row_start[b * BROWS + tid] = s + pref[tid];
    if (b == NB - 1 && tid == 0) row_start[M_ROWS] = e;
}

// ---------------- small converts ----------------

__global__ void xconv_kernel(const float* __restrict__ x, ushort* __restrict__ xb) {
    int i = blockIdx.x * 256 + threadIdx.x;
    __hip_bfloat16 v = __float2bfloat16(x[i]);
    xb[i] = *(ushort*)&v;
}

// Wcat[n][kkc]: kkc<64 -> sum_a W[0][a*64+kkc][n]; 64<=kkc<KCAT -> W[k][kk][n]; else 0.
__global__ void wcat_kernel(const float* __restrict__ W, ushort* __restrict__ Wcat) {
    int idx = blockIdx.x * 256 + threadIdx.x;    // 64*KCAT2
    int n   = idx / KCAT2;
    int kkc = idx - n * KCAT2;
    float v;
    if (kkc < 64) {
        v = 0.f;
#pragma unroll
        for (int a = 0; a < NANG; ++a) v += W[(a * 64 + kkc) * 64 + n];
    } else if (kkc < KCAT) {
        int k  = ((kkc - 64) >> 9) + 1;
        int kk = (kkc - 64) & 511;
        v = W[(size_t)k * WK_STRIDE + kk * 64 + n];
    } else {
        v = 0.f;
    }
    __hip_bfloat16 b = __float2bfloat16(v);
    Wcat[idx] = *(ushort*)&b;
}

// ---------------- SpMM: row-per-wave gather, readlane edge broadcast (MLP=16) ----------------
// R7-proven version: one 128B coalesced load pulls 16 edges; readlane(i) makes
// (col,w) wave-uniform SGPRs; 16 independent gathers in flight per batch.
// TIN_TILED: Tin is xb [N,64], col % N_NODES. TSUB_MODE: 0 none, 1 [M,64], 2 xb tiled.

template <int TIN_TILED, int TSUB_MODE>
__global__ __launch_bounds__(256) void spmm_kernel(
        const int* __restrict__ row_start, const int2* __restrict__ edges,
        const ushort* __restrict__ Tin, const ushort* __restrict__ Tsub,
        ushort* __restrict__ Tout, float alpha, float beta) {
    int r = (blockIdx.x * 256 + threadIdx.x) >> 6;
    int lane = threadIdx.x & 63;
    if (r >= M_ROWS) return;
    int s = row_start[r];
    int e = row_start[r + 1];
    float acc = 0.f;
    for (int base = s; base < e; base += 16) {
        int idx = min(base + (lane & 15), e - 1);
        int2 ed = edges[idx];                 // 16 edges, 128B coalesced (4x dup)
#pragma unroll
        for (int i = 0; i < 16; ++i) {
            int   col = __builtin_amdgcn_readlane(ed.x, i);
            float w   = __int_as_float(__builtin_amdgcn_readlane(ed.y, i));
            if (base + i >= e) w = 0.f;       // clamped dup edge contributes 0
            unsigned c = (unsigned)col;
            if (TIN_TILED) c %= N_NODES;
            float t = bf2f(Tin[(size_t)c * CH + lane]);
            acc = fmaf(w, t, acc);
        }
    }
    size_t oi = (size_t)r * CH + lane;
    float v = alpha * acc;
    if (TSUB_MODE == 1) v += beta * bf2f(Tsub[oi]);
    if (TSUB_MODE == 2) v += beta * bf2f(Tsub[(size_t)((unsigned)r % N_NODES) * CH + lane]);
    __hip_bfloat16 o = __float2bfloat16(v);
    Tout[oi] = *(ushort*)&o;
}

// ---------------- concatenated GEMM: 5000 independent single-wave blocks ----------
// out += partial([x | feat(T1..T7)] @ Wcat) via fp32 atomicAdd (out pre-zeroed).
// block = 1 wave = (16-row tile, 29-kstep chunk); A AND B prefetched 3-ahead in a
// 4-slot register ring (no LDS, no barrier -> all co-resident, BW-bound streaming).
// A layout: m=lane&15, k=(lane>>4)*8+j. C/D: col=lane&15, row=(lane>>4)*4+reg [m89].

__global__ __launch_bounds__(64) void gemm_cat_kernel(
        const ushort* __restrict__ xb,    // [N,64]
        const ushort* __restrict__ Tall,  // [7][NANG*N,64]
        const ushort* __restrict__ Wcat,  // [64][KCAT2]
        const float* __restrict__ bias,
        float* __restrict__ out) {        // [N,64] fp32, pre-zeroed
    int tile = blockIdx.x >> 2;
    int w    = blockIdx.x & 3;
    int m0 = tile * 16;
    int l = threadIdx.x;
    int lm = l & 15;
    int lq = l >> 4;
    const short* Xp = (const short*)xb;
    const short* Tp = (const short*)Tall;
    const short* Wp = (const short*)Wcat;

    auto loadA = [&](int sk) -> short8 {
        sk = min(sk, SK_TOTAL - 1);
        const short* p;
        if (sk < 2) {
            p = Xp + (size_t)(m0 + lm) * CH + sk * 32 + lq * 8;
        } else {
            int seg = (sk - 2) >> 4, ks = (sk - 2) & 15;
            int a = ks >> 1, hf = ks & 1;
            p = Tp + (size_t)seg * M_ROWS * CH
                + ((size_t)(a * N_NODES + m0 + lm)) * CH + hf * 32 + lq * 8;
        }
        return *(const short8*)p;
    };

    f32x4 acc[4];
#pragma unroll
    for (int t = 0; t < 4; ++t) acc[t] = (f32x4){0.f, 0.f, 0.f, 0.f};

    int sk0 = w * 29;
    short8 ab[4];
    short8 bb[4][4];
#pragma unroll
    for (int p = 0; p < 3; ++p) {
        ab[p] = loadA(sk0 + p);
#pragma unroll
        for (int t = 0; t < 4; ++t)
            bb[p][t] = *(const short8*)(Wp + (size_t)(t * 16 + lm) * KCAT2 + (sk0 + p) * 32 + lq * 8);
    }

#pragma unroll
    for (int i = 0; i < 29; ++i) {
        int pre = i + 3;
        if (pre < 29) {
            int slot = pre & 3;            // slot consumed at iter i-1 -> free
            ab[slot] = loadA(sk0 + pre);
#pragma unroll
            for (int t = 0; t < 4; ++t)
                bb[slot][t] = *(const short8*)(Wp + (size_t)(t * 16 + lm) * KCAT2 + (sk0 + pre) * 32 + lq * 8);
        }
        int cur = i & 3;
#pragma unroll
        for (int t = 0; t < 4; ++t)
            acc[t] = __builtin_amdgcn_mfma_f32_16x16x32_bf16(ab[cur], bb[cur][t], acc[t], 0, 0, 0);
    }

#pragma unroll
    for (int t = 0; t < 4; ++t) {
        int col = t * 16 + lm;
#pragma unroll
        for (int rI = 0; rI < 4; ++rI) {
            float v = acc[t][rI];
            if (w == 0) v += bias[col];
            atomicAdd(&out[(size_t)(m0 + lq * 4 + rI) * CH + col], v);
        }
    }
}

// ---------------- launch ----------------

extern "C" void kernel_launch(void* const* d_in, const int* in_sizes, int n_in,
                              void* d_out, int out_size, void* d_ws, size_t ws_size,
                              hipStream_t stream) {
    (void)in_sizes; (void)n_in; (void)out_size; (void)ws_size;
    const float* x       = (const float*)d_in[0];
    const float* ls_vals = (const float*)d_in[1];
    const float* weight  = (const float*)d_in[2];
    const float* bias    = (const float*)d_in[3];
    const int*   ls_rows = (const int*)d_in[4];
    const int*   ls_cols = (const int*)d_in[5];
    float* out = (float*)d_out;

    char* ws = (char*)d_ws;
    size_t off = 0;
    auto alloc = [&](size_t bytes) -> void* {
        void* p = ws + off;
        off += (bytes + 255) & ~(size_t)255;
        return p;
    };
    int*  chunk_cnt = (int*)alloc((size_t)NCHUNK * NB * sizeof(int));
    int*  btotal    = (int*)alloc(NB * sizeof(int));
    int*  bstart    = (int*)alloc((NB + 1) * sizeof(int));
    int*  row_start = (int*)alloc((M_ROWS + 1) * sizeof(int));
    int2* bedges2   = (int2*)alloc((size_t)E_EDGES * sizeof(int2));
    ushort* Wcat = (ushort*)alloc((size_t)64 * KCAT2 * sizeof(ushort));
    ushort* xb   = (ushort*)alloc((size_t)N_NODES * CH * sizeof(ushort));
    ushort* Tall = (ushort*)alloc((size_t)7 * M_ROWS * CH * sizeof(ushort));
    // Alias: phase-1 bucket staging lives in Tall seg0 (dead before spmm#1 writes it)
    int2* bedges = (int2*)Tall;

    // zero the output accumulator (gemm_cat uses atomicAdd)
    hipMemsetAsync(out, 0, (size_t)N_NODES * CH * sizeof(float), stream);

    // deterministic bucket build + per-bucket row grouping
    count_kernel<<<NCHUNK, 256, 0, stream>>>(ls_rows, chunk_cnt);
    btotal_kernel<<<(NB + 255) / 256, 256, 0, stream>>>(chunk_cnt, btotal);
    bscan_kernel<<<1, 1024, 0, stream>>>(btotal, bstart);
    offs_kernel<<<(NB + 255) / 256, 256, 0, stream>>>(chunk_cnt, bstart);
    scatter_kernel<<<NCHUNK, 256, 0, stream>>>(ls_rows, ls_cols, ls_vals, chunk_cnt, bedges);
    bucket_group_kernel<<<NB, 256, 0, stream>>>(bstart, bedges, bedges2, row_start);

    // converts
    xconv_kernel<<<(N_NODES * CH) / 256, 256, 0, stream>>>(x, xb);
    wcat_kernel<<<(64 * KCAT2) / 256, 256, 0, stream>>>(weight, Wcat);

    ushort* T[8];  // T[k] = seg k-1
    for (int k = 1; k < K_CHEB; ++k) T[k] = Tall + (size_t)(k - 1) * M_ROWS * CH;

    // Chebyshev chain (T1 = L tile(x); Tk = 2 L T_{k-1} - T_{k-2})
    spmm_kernel<1, 0><<<SPMM_BLOCKS, 256, 0, stream>>>(
        row_start, bedges2, xb, xb, T[1], 1.f, 0.f);
    spmm_kernel<0, 2><<<SPMM_BLOCKS, 256, 0, stream>>>(
        row_start, bedges2, T[1], xb, T[2], 2.f, -1.f);
    for (int k = 3; k < K_CHEB; ++k) {
        spmm_kernel<0, 1><<<SPMM_BLOCKS, 256, 0, stream>>>(
            row_start, bedges2, T[k - 1], T[k - 2], T[k], 2.f, -1.f);
    }

    // one concatenated GEMM for all k terms (4 k-chunks per 16-row tile)
    gemm_cat_kernel<<<(N_NODES / 16) * 4, 64, 0, stream>>>(xb, Tall, Wcat, bias, out);
}

// Round 14
// 738.105 us; speedup vs baseline: 1.4306x; 1.0081x over previous
//
#include <hip/hip_runtime.h>
#include <hip/hip_bf16.h>

// Problem constants (from setup_inputs)
#define N_NODES 20000
#define NANG 8
#define CH 64                      // in_size == out_size == 64
#define M_ROWS (NANG * N_NODES)    // 160000
#define E_EDGES (M_ROWS * 16)      // 2560000
#define K_CHEB 8
#define WK_STRIDE (NANG * CH * CH) // 32768 floats per weight[k]
#define BROWS 256                  // rows per bucket (good scatter write-combining)
#define NB (M_ROWS / BROWS)        // 625 buckets
#define NCHUNK 320
#define CHUNK (E_EDGES / NCHUNK)   // 8000
#define HALF_ROWS (M_ROWS / 2)     // 80000
#define SPMM_BLOCKS (HALF_ROWS / 4) // 20000 (2 strided rows/wave, 4 waves/block)
#define KCAT 3648                  // 64 (x@Wsum) + 7*512 (feat(Tk)@Wk)
#define SK_TOTAL 114               // KCAT/32 ksteps
#define SK_PAD 116                 // padded to 4*29 (pad ksteps have zero W)
#define KCAT2 (SK_PAD * 32)        // 3712
#define BCAP 5120                  // LDS staging cap (mean 4096, sd 64 -> 16 sigma)

typedef short short8 __attribute__((ext_vector_type(8)));
typedef float f32x4 __attribute__((ext_vector_type(4)));

__device__ __forceinline__ float bf2f(ushort u) {
    return __uint_as_float((unsigned int)u << 16);
}

// ---------------- deterministic bucket build (no global atomics) ----------------

__global__ __launch_bounds__(256) void count_kernel(const int* __restrict__ rows,
                                                    int* __restrict__ chunk_cnt) {
    __shared__ int h[NB];
    int c = blockIdx.x, tid = threadIdx.x;
    for (int i = tid; i < NB; i += 256) h[i] = 0;
    __syncthreads();
    int base = c * CHUNK;
    for (int i = tid; i < CHUNK; i += 256) atomicAdd(&h[rows[base + i] >> 8], 1);
    __syncthreads();
    for (int i = tid; i < NB; i += 256) chunk_cnt[(size_t)c * NB + i] = h[i];
}

__global__ void btotal_kernel(const int* __restrict__ chunk_cnt, int* __restrict__ btotal) {
    int b = blockIdx.x * 256 + threadIdx.x;
    if (b >= NB) return;
    int s = 0;
    for (int c = 0; c < NCHUNK; ++c) s += chunk_cnt[(size_t)c * NB + b];
    btotal[b] = s;
}

// single-block exclusive scan over NB bucket totals (NB=625 <= 1024)
__global__ void bscan_kernel(const int* __restrict__ btotal, int* __restrict__ bstart) {
    __shared__ int s[1024];
    int t = threadIdx.x;
    int v = (t < NB) ? btotal[t] : 0;
    s[t] = v;
    __syncthreads();
    for (int off = 1; off < 1024; off <<= 1) {
        int u = (t >= off) ? s[t - off] : 0;
        __syncthreads();
        s[t] += u;
        __syncthreads();
    }
    if (t < NB) bstart[t] = s[t] - v;
    if (t == 1023) bstart[NB] = s[1023];
}

// chunk_cnt -> per-(chunk,bucket) write offsets, in place
__global__ void offs_kernel(int* __restrict__ chunk_cnt, const int* __restrict__ bstart) {
    int b = blockIdx.x * 256 + threadIdx.x;
    if (b >= NB) return;
    int run = bstart[b];
    for (int c = 0; c < NCHUNK; ++c) {
        int v = chunk_cnt[(size_t)c * NB + b];
        chunk_cnt[(size_t)c * NB + b] = run;
        run += v;
    }
}

// scatter into bucket-ordered streams (LDS-local offsets, sequential per-bucket writes)
__global__ __launch_bounds__(256) void scatter_kernel(
        const int* __restrict__ rows, const int* __restrict__ cols,
        const float* __restrict__ vals, const int* __restrict__ chunk_cnt,
        int2* __restrict__ bedges) {
    __shared__ int loff[NB];
    int c = blockIdx.x, tid = threadIdx.x;
    for (int i = tid; i < NB; i += 256) loff[i] = chunk_cnt[(size_t)c * NB + i];
    __syncthreads();
    int base = c * CHUNK;
    for (int i = tid; i < CHUNK; i += 256) {
        int e = base + i;
        int r = rows[e];
        int p = atomicAdd(&loff[r >> 8], 1);
        bedges[p] = make_int2(cols[e] | ((r & 255) << 18), __float_as_int(vals[e]));
    }
}

// per-bucket: group edges by row via LDS staging, then write bout SEQUENTIALLY
__global__ __launch_bounds__(256) void bucket_group_kernel(
        const int* __restrict__ bstart, const int2* __restrict__ bin,
        int2* __restrict__ bout, int* __restrict__ row_start) {
    __shared__ int cnt[BROWS];
    __shared__ int pref[BROWS];
    __shared__ int fill[BROWS];
    __shared__ int2 ob[BCAP];          // 40 KB staging
    int b = blockIdx.x, tid = threadIdx.x;
    int s = bstart[b], e = bstart[b + 1];
    int n = e - s;
    cnt[tid] = 0;
    __syncthreads();
    int2 eds[20];                      // reg cache (n/256 <= 20 when n <= BCAP)
    int ni = 0;
    for (int i = tid; i < n; i += 256, ++ni) {
        int2 ed = bin[s + i];
        if (ni < 20) eds[ni] = ed;
        atomicAdd(&cnt[(ed.x >> 18) & 255], 1);
    }
    __syncthreads();
    int v = cnt[tid];
    pref[tid] = v;
    __syncthreads();
#pragma unroll
    for (int off = 1; off < 256; off <<= 1) {
        int u = (tid >= off) ? pref[tid - off] : 0;
        __syncthreads();
        pref[tid] += u;
        __syncthreads();
    }
    int my_excl = pref[tid] - v;
    __syncthreads();
    pref[tid] = my_excl;
    fill[tid] = my_excl;
    __syncthreads();

    if (n <= BCAP) {
        ni = 0;
        for (int i = tid; i < n; i += 256, ++ni) {
            int2 ed = (ni < 20) ? eds[ni] : bin[s + i];
            int p = atomicAdd(&fill[(ed.x >> 18) & 255], 1);
            ob[p] = make_int2(ed.x & 0x3ffff, ed.y);
        }
        __syncthreads();
        for (int i = tid; i < n; i += 256)
            bout[s + i] = ob[i];       // sequential, coalesced
    } else {
        ni = 0;
        for (int i = tid; i < n; i += 256, ++ni) {
            int2 ed = (ni < 20) ? eds[ni] : bin[s + i];
            int p = atomicAdd(&fill[(ed.x >> 18) & 255], 1);
            bout[s + p] = make_int2(ed.x & 0x3ffff, ed.y);
        }
    }
    row_start[b * BROWS + tid] = s + pref[tid];
    if (b == NB - 1 && tid == 0) row_start[M_ROWS] = e;
}

// ---------------- small converts ----------------

__global__ void xconv_kernel(const float* __restrict__ x, ushort* __restrict__ xb) {
    int i = blockIdx.x * 256 + threadIdx.x;
    __hip_bfloat16 v = __float2bfloat16(x[i]);
    xb[i] = *(ushort*)&v;
}

// Wcat[n][kkc]: kkc<64 -> sum_a W[0][a*64+kkc][n]; 64<=kkc<KCAT -> W[k][kk][n]; else 0.
__global__ void wcat_kernel(const float* __restrict__ W, ushort* __restrict__ Wcat) {
    int idx = blockIdx.x * 256 + threadIdx.x;    // 64*KCAT2
    int n   = idx / KCAT2;
    int kkc = idx - n * KCAT2;
    float v;
    if (kkc < 64) {
        v = 0.f;
#pragma unroll
        for (int a = 0; a < NANG; ++a) v += W[(a * 64 + kkc) * 64 + n];
    } else if (kkc < KCAT) {
        int k  = ((kkc - 64) >> 9) + 1;
        int kk = (kkc - 64) & 511;
        v = W[(size_t)k * WK_STRIDE + kk * 64 + n];
    } else {
        v = 0.f;
    }
    __hip_bfloat16 b = __float2bfloat16(v);
    Wcat[idx] = *(ushort*)&b;
}

// ---------------- SpMM: 2 strided rows per wave, 4 edge batches preloaded ----------
// Wave wv handles rows wv and wv+80000. All four 16-edge batches (2 per row,
// covers n<=32; rare tail loop beyond) are loaded as independent requests at wave
// start -> 1 edge-load latency per 2 rows (R7 paid ~2.9). Per-slot body identical
// to R7 (readlane broadcast, dup-clamp mask) -- no extra per-edge VALU (R12 lesson).
// TIN_TILED: Tin is xb [N,64], col % N_NODES. TSUB_MODE: 0 none, 1 [M,64], 2 xb tiled.

template <int TIN_TILED, int TSUB_MODE>
__global__ __launch_bounds__(256) void spmm_kernel(
        const int* __restrict__ row_start, const int2* __restrict__ edges,
        const ushort* __restrict__ Tin, const ushort* __restrict__ Tsub,
        ushort* __restrict__ Tout, float alpha, float beta) {
    int wv = (blockIdx.x * 256 + threadIdx.x) >> 6;
    int lane = threadIdx.x & 63;
    if (wv >= HALF_ROWS) return;
    int r0 = wv, r1 = wv + HALF_ROWS;
    int s0 = row_start[r0], e0 = row_start[r0 + 1];
    int s1 = row_start[r1], e1 = row_start[r1 + 1];
    int j = lane & 15;
    // 4 independent edge-batch loads, all in flight together
    int2 edA0 = edges[min(s0 + j,      e0 - 1)];
    int2 edB0 = edges[min(s1 + j,      e1 - 1)];
    int2 edA1 = edges[min(s0 + 16 + j, e0 - 1)];
    int2 edB1 = edges[min(s1 + 16 + j, e1 - 1)];
    float acc0 = 0.f, acc1 = 0.f;

    auto body = [&](int2 ed, int base, int e, float& acc) {
#pragma unroll
        for (int i = 0; i < 16; ++i) {
            int   col = __builtin_amdgcn_readlane(ed.x, i);
            float w   = __int_as_float(__builtin_amdgcn_readlane(ed.y, i));
            if (base + i >= e) w = 0.f;       // clamped dup edge contributes 0
            unsigned c = (unsigned)col;
            if (TIN_TILED) c %= N_NODES;
            acc = fmaf(w, bf2f(Tin[(size_t)c * CH + lane]), acc);
        }
    };

    body(edA0, s0, e0, acc0);
    body(edB0, s1, e1, acc1);
    if (e0 > s0 + 16) body(edA1, s0 + 16, e0, acc0);
    if (e1 > s1 + 16) body(edB1, s1 + 16, e1, acc1);
    // rare tails (n > 32)
    for (int base = s0 + 32; base < e0; base += 16) {
        int2 ed = edges[min(base + j, e0 - 1)];
        body(ed, base, e0, acc0);
    }
    for (int base = s1 + 32; base < e1; base += 16) {
        int2 ed = edges[min(base + j, e1 - 1)];
        body(ed, base, e1, acc1);
    }

    auto epi = [&](int r, float acc) {
        size_t oi = (size_t)r * CH + lane;
        float v = alpha * acc;
        if (TSUB_MODE == 1) v += beta * bf2f(Tsub[oi]);
        if (TSUB_MODE == 2) v += beta * bf2f(Tsub[(size_t)((unsigned)r % N_NODES) * CH + lane]);
        __hip_bfloat16 o = __float2bfloat16(v);
        Tout[oi] = *(ushort*)&o;
    };
    epi(r0, acc0);
    epi(r1, acc1);
}

// ---------------- concatenated GEMM: 5000 independent waves, 4 per block ----------
// out += partial([x | feat(T1..T7)] @ Wcat) via fp32 atomicAdd (out pre-zeroed).
// Virtual single-wave blocks packed 4-per-256-thread-block (no LDS/barrier) to
// dodge the per-CU resident-block cap that starved the 64-thread version (R13:
// occupancy 35%). Each wave: (16-row tile, 29-kstep chunk), A+B 3-ahead ring.
// A layout: m=lane&15, k=(lane>>4)*8+j. C/D: col=lane&15, row=(lane>>4)*4+reg [m89].

__global__ __launch_bounds__(256) void gemm_cat_kernel(
        const ushort* __restrict__ xb,    // [N,64]
        const ushort* __restrict__ Tall,  // [7][NANG*N,64]
        const ushort* __restrict__ Wcat,  // [64][KCAT2]
        const float* __restrict__ bias,
        float* __restrict__ out) {        // [N,64] fp32, pre-zeroed
    int g = blockIdx.x * 4 + (threadIdx.x >> 6);   // virtual wave id
    int tile = g >> 2;
    int w    = g & 3;
    int m0 = tile * 16;
    int l = threadIdx.x & 63;
    int lm = l & 15;
    int lq = l >> 4;
    const short* Xp = (const short*)xb;
    const short* Tp = (const short*)Tall;
    const short* Wp = (const short*)Wcat;

    auto loadA = [&](int sk) -> short8 {
        sk = min(sk, SK_TOTAL - 1);
        const short* p;
        if (sk < 2) {
            p = Xp + (size_t)(m0 + lm) * CH + sk * 32 + lq * 8;
        } else {
            int seg = (sk - 2) >> 4, ks = (sk - 2) & 15;
            int a = ks >> 1, hf = ks & 1;
            p = Tp + (size_t)seg * M_ROWS * CH
                + ((size_t)(a * N_NODES + m0 + lm)) * CH + hf * 32 + lq * 8;
        }
        return *(const short8*)p;
    };

    f32x4 acc[4];
#pragma unroll
    for (int t = 0; t < 4; ++t) acc[t] = (f32x4){0.f, 0.f, 0.f, 0.f};

    int sk0 = w * 29;
    short8 ab[4];
    short8 bb[4][4];
#pragma unroll
    for (int p = 0; p < 3; ++p) {
        ab[p] = loadA(sk0 + p);
#pragma unroll
        for (int t = 0; t < 4; ++t)
            bb[p][t] = *(const short8*)(Wp + (size_t)(t * 16 + lm) * KCAT2 + (sk0 + p) * 32 + lq * 8);
    }

#pragma unroll
    for (int i = 0; i < 29; ++i) {
        int pre = i + 3;
        if (pre < 29) {
            int slot = pre & 3;            // slot consumed at iter i-1 -> free
            ab[slot] = loadA(sk0 + pre);
#pragma unroll
            for (int t = 0; t < 4; ++t)
                bb[slot][t] = *(const short8*)(Wp + (size_t)(t * 16 + lm) * KCAT2 + (sk0 + pre) * 32 + lq * 8);
        }
        int cur = i & 3;
#pragma unroll
        for (int t = 0; t < 4; ++t)
            acc[t] = __builtin_amdgcn_mfma_f32_16x16x32_bf16(ab[cur], bb[cur][t], acc[t], 0, 0, 0);
    }

#pragma unroll
    for (int t = 0; t < 4; ++t) {
        int col = t * 16 + lm;
#pragma unroll
        for (int rI = 0; rI < 4; ++rI) {
            float v = acc[t][rI];
            if (w == 0) v += bias[col];
            atomicAdd(&out[(size_t)(m0 + lq * 4 + rI) * CH + col], v);
        }
    }
}

// ---------------- launch ----------------

extern "C" void kernel_launch(void* const* d_in, const int* in_sizes, int n_in,
                              void* d_out, int out_size, void* d_ws, size_t ws_size,
                              hipStream_t stream) {
    (void)in_sizes; (void)n_in; (void)out_size; (void)ws_size;
    const float* x       = (const float*)d_in[0];
    const float* ls_vals = (const float*)d_in[1];
    const float* weight  = (const float*)d_in[2];
    const float* bias    = (const float*)d_in[3];
    const int*   ls_rows = (const int*)d_in[4];
    const int*   ls_cols = (const int*)d_in[5];
    float* out = (float*)d_out;

    char* ws = (char*)d_ws;
    size_t off = 0;
    auto alloc = [&](size_t bytes) -> void* {
        void* p = ws + off;
        off += (bytes + 255) & ~(size_t)255;
        return p;
    };
    int*  chunk_cnt = (int*)alloc((size_t)NCHUNK * NB * sizeof(int));
    int*  btotal    = (int*)alloc(NB * sizeof(int));
    int*  bstart    = (int*)alloc((NB + 1) * sizeof(int));
    int*  row_start = (int*)alloc((M_ROWS + 1) * sizeof(int));
    int2* bedges2   = (int2*)alloc((size_t)E_EDGES * sizeof(int2));
    ushort* Wcat = (ushort*)alloc((size_t)64 * KCAT2 * sizeof(ushort));
    ushort* xb   = (ushort*)alloc((size_t)N_NODES * CH * sizeof(ushort));
    ushort* Tall = (ushort*)alloc((size_t)7 * M_ROWS * CH * sizeof(ushort));
    // Alias: phase-1 bucket staging lives in Tall seg0 (dead before spmm#1 writes it)
    int2* bedges = (int2*)Tall;

    // zero the output accumulator (gemm_cat uses atomicAdd)
    hipMemsetAsync(out, 0, (size_t)N_NODES * CH * sizeof(float), stream);

    // deterministic bucket build + per-bucket row grouping
    count_kernel<<<NCHUNK, 256, 0, stream>>>(ls_rows, chunk_cnt);
    btotal_kernel<<<(NB + 255) / 256, 256, 0, stream>>>(chunk_cnt, btotal);
    bscan_kernel<<<1, 1024, 0, stream>>>(btotal, bstart);
    offs_kernel<<<(NB + 255) / 256, 256, 0, stream>>>(chunk_cnt, bstart);
    scatter_kernel<<<NCHUNK, 256, 0, stream>>>(ls_rows, ls_cols, ls_vals, chunk_cnt, bedges);
    bucket_group_kernel<<<NB, 256, 0, stream>>>(bstart, bedges, bedges2, row_start);

    // converts
    xconv_kernel<<<(N_NODES * CH) / 256, 256, 0, stream>>>(x, xb);
    wcat_kernel<<<(64 * KCAT2) / 256, 256, 0, stream>>>(weight, Wcat);

    ushort* T[8];  // T[k] = seg k-1
    for (int k = 1; k < K_CHEB; ++k) T[k] = Tall + (size_t)(k - 1) * M_ROWS * CH;

    // Chebyshev chain (T1 = L tile(x); Tk = 2 L T_{k-1} - T_{k-2})
    spmm_kernel<1, 0><<<SPMM_BLOCKS, 256, 0, stream>>>(
        row_start, bedges2, xb, xb, T[1], 1.f, 0.f);
    spmm_kernel<0, 2><<<SPMM_BLOCKS, 256, 0, stream>>>(
        row_start, bedges2, T[1], xb, T[2], 2.f, -1.f);
    for (int k = 3; k < K_CHEB; ++k) {
        spmm_kernel<0, 1><<<SPMM_BLOCKS, 256, 0, stream>>>(
            row_start, bedges2, T[k - 1], T[k - 2], T[k], 2.f, -1.f);
    }

    // one concatenated GEMM for all k terms (4 virtual wave-chunks per 16-row tile)
    gemm_cat_kernel<<<N_NODES / 16, 256, 0, stream>>>(xb, Tall, Wcat, bias, out);
}